// Round 5
// baseline (3628.964 us; speedup 1.0000x reference)
//
#include <hip/hip_runtime.h>
#include <math.h>

// Router: scores = x @ emb^T [32768 x 64] fp32, top-2 + 2-way softmax scatter.
//
// lane = TOKEN (64 tokens/block), wave w owns experts [16w,16w+16).
// emb is PREPACKED into d_ws as er[g][e] (g = 4-k step, e = expert): per step a
// wave reads 16 CONSECUTIVE float4s (one base + imm offsets), explicitly
// double-buffered in registers one step ahead (eA/eB, static unroll) so the 16
// uniform VMEM loads overlap the 64 FMAs of the previous step.  Round 4 showed
// un-pipelined uniform loads serialize at ~225 cyc each (VALUBusy 19%).
// x staged via global_load_lds (linear dest, XOR-pre-swizzled source), read as
// lane-varying ds_read_b128, prefetched one step ahead (0 conflicts measured).

constexpr int HDIM = 1024;
constexpr int NEXP = 64;
constexpr int TPB  = 64;            // tokens per block
constexpr int BK   = 64;            // k per chunk
constexpr int NQ   = BK / 4;        // 16 quads per chunk
constexpr int NTHREADS = 256;
constexpr int NCHUNK = HDIM / BK;   // 16
constexpr int NSTEP  = HDIM / 4;    // 256 global 4-k steps

// ---- prepack: er[g*64 + e] = emb[e][4g..4g+3], g in [0,256) ----
__global__ __launch_bounds__(256)
void prepack_kernel(const float* __restrict__ emb, float4* __restrict__ er)
{
    const int f = blockIdx.x * 256 + threadIdx.x;   // 0..16383
    const int e = f & 63;
    const int g = f >> 6;
    er[f] = *(const float4*)(emb + (size_t)e * HDIM + g * 4);
}

__global__ __launch_bounds__(NTHREADS, 2)
void router_kernel(const float* __restrict__ x,
                   const float4* __restrict__ er,
                   float* __restrict__ out)
{
    __shared__ float4 xs[2][TPB][NQ];   // 32 KiB, x[token][quad^(token&15)]
    __shared__ float4 cand[4][TPB];     // 4 KiB, per-wave top-2 candidates

    const int tid  = threadIdx.x;
    const int lane = tid & 63;          // token-in-block
    const int w    = tid >> 6;          // expert group (divergent to compiler
                                        // -> VMEM loads, not scalar)
    const int tok0 = blockIdx.x * TPB;
    const int sw   = lane & 15;

#define STAGE(P, C)                                                            \
    do {                                                                       \
        _Pragma("unroll")                                                      \
        for (int j = 0; j < 4; ++j) {                                          \
            const int g_ = j * 256 + tid;                                      \
            const int r_ = g_ >> 4, q_ = g_ & 15;                              \
            const float* src = x + (size_t)(tok0 + r_) * HDIM + (C) * BK       \
                                 + ((q_ ^ (r_ & 15)) * 4);                     \
            __builtin_amdgcn_global_load_lds(                                  \
                (const __attribute__((address_space(1))) void*)src,            \
                (__attribute__((address_space(3))) void*)&xs[P][r_][q_],       \
                16, 0, 0);                                                     \
        }                                                                      \
    } while (0)

    float acc[16];
#pragma unroll
    for (int i = 0; i < 16; ++i) acc[i] = 0.f;

    const float4* ew = er + 16 * w;     // this wave's expert slice

    float4 eA[16], eB[16];
#pragma unroll
    for (int e = 0; e < 16; ++e) eA[e] = ew[e];     // step g=0

    STAGE(0, 0);
    int p = 0;

    // One step: compute on CUR, prefetch next step's emb into NXT.
#define STEP(CUR, NXT, QQ)                                                     \
    do {                                                                       \
        float4 xnxt = xcur;                                                    \
        if ((QQ) < 15) xnxt = xs[p][lane][((QQ) + 1) ^ sw];                    \
        const int gn = c * 16 + (QQ) + 1;                                      \
        if (gn < NSTEP) {                                                      \
            const float4* nb = ew + (size_t)gn * 64;                           \
            _Pragma("unroll")                                                  \
            for (int e = 0; e < 16; ++e) NXT[e] = nb[e];                       \
        }                                                                      \
        _Pragma("unroll")                                                      \
        for (int e = 0; e < 16; ++e) {                                         \
            float a = acc[e];                                                  \
            a = fmaf(CUR[e].x, xcur.x, a);                                     \
            a = fmaf(CUR[e].y, xcur.y, a);                                     \
            a = fmaf(CUR[e].z, xcur.z, a);                                     \
            a = fmaf(CUR[e].w, xcur.w, a);                                     \
            acc[e] = a;                                                        \
        }                                                                      \
        xcur = xnxt;                                                           \
    } while (0)

#pragma unroll 1
    for (int c = 0; c < NCHUNK; ++c) {
        __syncthreads();                       // chunk c staged in xs[p]
        if (c + 1 < NCHUNK) STAGE(p ^ 1, c + 1);

        float4 xcur = xs[p][lane][0 ^ sw];
#pragma unroll
        for (int qq = 0; qq < 16; qq += 2) {
            STEP(eA, eB, qq);
            STEP(eB, eA, qq + 1);
        }
        p ^= 1;
    }
#undef STEP

    // ---- per-lane local top-2 over this wave's 16 experts (register-only) ----
    float v1 = acc[0], v2 = -INFINITY;
    int   j1 = 0,      j2 = 0;
#pragma unroll
    for (int j = 1; j < 16; ++j) {
        if (acc[j] > v1)      { v2 = v1; j2 = j1; v1 = acc[j]; j1 = j; }
        else if (acc[j] > v2) { v2 = acc[j]; j2 = j; }
    }
    float4 cd;
    cd.x = v1; cd.y = __int_as_float(16 * w + j1);
    cd.z = v2; cd.w = __int_as_float(16 * w + j2);
    cand[w][lane] = cd;
    __syncthreads();

    // ---- merge 4 waves' candidates (tie: lowest expert index wins) ----
    float V1 = -INFINITY, V2 = -INFINITY;
    int   E1 = 0,         E2 = 0;
#pragma unroll
    for (int ww = 0; ww < 4; ++ww) {
        const float4 q = cand[ww][lane];
        const float a = q.x; const int ea = __float_as_int(q.y);
        const float b = q.z; const int eb = __float_as_int(q.w);
        if (a > V1)      { V2 = V1; E2 = E1; V1 = a; E1 = ea; }
        else if (a > V2) { V2 = a; E2 = ea; }
        if (b > V1)      { V2 = V1; E2 = E1; V1 = b; E1 = eb; }
        else if (b > V2) { V2 = b; E2 = eb; }
    }
    const float et = expf(V2 - V1);
    const float p1 = 1.f / (1.f + et);
    const float p2 = et / (1.f + et);

    // ---- build output rows in LDS (reuse xs[0]), then coalesced store ----
    float4* rb = (float4*)&xs[0][0][0];        // [64 tokens][16 quads], swizzled
#pragma unroll
    for (int qq = 0; qq < 4; ++qq) {
        const int q = 4 * w + qq;              // quad = experts 4q..4q+3
        float4 o;
        float* of = (float*)&o;
#pragma unroll
        for (int i = 0; i < 4; ++i) {
            const int e = 4 * q + i;
            of[i] = (e == E1) ? p1 : (e == E2) ? p2 : 0.f;
        }
        rb[lane * 16 + (q ^ sw)] = o;
    }
    __syncthreads();

    const int t  = tid >> 2;
    const int qb = (tid & 3) * 4;
#pragma unroll
    for (int i = 0; i < 4; ++i) {
        const int q = qb + i;
        const float4 o = rb[t * 16 + (q ^ (t & 15))];
        *(float4*)(out + (size_t)(tok0 + t) * NEXP + q * 4) = o;
    }
#undef STAGE
}

extern "C" void kernel_launch(void* const* d_in, const int* in_sizes, int n_in,
                              void* d_out, int out_size, void* d_ws, size_t ws_size,
                              hipStream_t stream)
{
    const float* x   = (const float*)d_in[0];
    const float* emb = (const float*)d_in[1];
    float* out = (float*)d_out;
    float4* er = (float4*)d_ws;                  // 256 KiB prepacked emb

    prepack_kernel<<<64, 256, 0, stream>>>(emb, er);

    const int n_tokens = in_sizes[0] / HDIM;     // 32768
    const int nblocks  = n_tokens / TPB;         // 512

    router_kernel<<<nblocks, NTHREADS, 0, stream>>>(x, er, out);
}

// Round 7
// 90.682 us; speedup vs baseline: 40.0186x; 40.0186x over previous
//
#include <hip/hip_runtime.h>
#include <math.h>

// Router: scores = x @ emb^T [32768 x 64] fp32, top-2 + 2-way softmax scatter.
//
// Uniform-operand delivery via v_readlane: the emb chunk (4 KB/wave: 8 experts
// x 64 k) sits LANE-VARYING in 8 VGPRs/lane (2 coalesced dwordx4 loads from a
// prepacked layout, prefetched 1 chunk ahead -> latency-trivial, no big
// buffers). At consume time each emb scalar is broadcast with v_readlane (2-cyc
// VALU, no LDS pipe) into an SGPR feeding v_fmac_f32's scalar operand. Each
// lane owns TWO tokens so one readlane feeds 2 FMAs -> 1.5x VALU = 41 us floor.
// Round-5 lesson: register-buffered VMEM prefetch spills (8.6 GB scratch);
// round-2 lesson: LDS broadcast is pipe-bound (4 SIMDs share 1 LDS pipe).
// Round-6 crash: epilogue loop wrote 8192 float4/block instead of 2048 (OOB);
// fixed to 4 iterations (2048 = 128 tokens x 16 quads).
//
// Block = 512 thr = 8 waves; wave w = experts [8w,8w+8); block = 128 tokens;
// lane owns tokens (lane, lane+64). x staged via global_load_lds with
// XOR-quad-swizzle via pre-swizzled source (0 conflicts measured).

constexpr int HDIM = 1024;
constexpr int NEXP = 64;
constexpr int TPB  = 128;           // tokens per block
constexpr int NQ   = 16;            // quads per 64-k chunk row
constexpr int NTHREADS = 512;
constexpr int NCHUNK = 16;

// prepack: ewp[w*2048 + c*128 + l*2 + r] = emb[8w+(l&7)][64c + 8*(l>>3) + 4r ..+3]
// -> per (wave,chunk): 4 KB contiguous; lane l reads 2 consecutive float4s.
__global__ __launch_bounds__(256)
void prepack_kernel(const float* __restrict__ emb, float4* __restrict__ ewp)
{
    const int f = blockIdx.x * 256 + threadIdx.x;   // 0..16383
    const int r = f & 1;
    const int l = (f >> 1) & 63;
    const int c = (f >> 7) & 15;
    const int w = f >> 11;
    const int e = 8 * w + (l & 7);
    const int k = 64 * c + 8 * (l >> 3) + 4 * r;
    ewp[f] = *(const float4*)(emb + (size_t)e * HDIM + k);
}

__global__ __launch_bounds__(NTHREADS, 2)
void router_kernel(const float* __restrict__ x,
                   const float4* __restrict__ ewp,
                   float* __restrict__ out)
{
    __shared__ float4 xs[2][TPB][NQ];     // 64 KiB, x[token][quad^(token&15)]
    __shared__ float4 cand[8][2][64];     // 16 KiB  (v1,e1,v2,e2) per wave/half
    __shared__ float4 cand2[TPB];         // 2 KiB   (p1,p2,E1,E2) per token

    const int tid  = threadIdx.x;
    const int lane = tid & 63;
    const int w    = tid >> 6;            // e-group: experts [8w, 8w+8)
    const int tok0 = blockIdx.x * TPB;
    const int sw   = lane & 15;

    // Stage chunk C of x (128 rows x 64 k = 32 KB) into buffer P.
    // Dest linear in thread order (gload_lds requirement); XOR swizzle folded
    // into per-lane GLOBAL source.
#define STAGE(P, C)                                                            \
    do {                                                                       \
        _Pragma("unroll")                                                      \
        for (int jj = 0; jj < 4; ++jj) {                                       \
            const int g_ = jj * NTHREADS + tid;                                \
            const int r_ = g_ >> 4, q_ = g_ & 15;                              \
            const float* src = x + (size_t)(tok0 + r_) * HDIM + (C) * 64       \
                                 + ((q_ ^ (r_ & 15)) * 4);                     \
            __builtin_amdgcn_global_load_lds(                                  \
                (const __attribute__((address_space(1))) void*)src,            \
                (__attribute__((address_space(3))) void*)&xs[P][r_][q_],       \
                16, 0, 0);                                                     \
        }                                                                      \
    } while (0)

    float accA[8], accB[8];
#pragma unroll
    for (int i = 0; i < 8; ++i) { accA[i] = 0.f; accB[i] = 0.f; }

    const float4* ew = ewp + (size_t)w * 2048;     // this wave's packed slice
    float4 eC0 = ew[2 * lane], eC1 = ew[2 * lane + 1];   // chunk 0

    STAGE(0, 0);
    int p = 0;

#pragma unroll 1
    for (int c = 0; c < NCHUNK; ++c) {
        __syncthreads();                           // xs[p] staged
        if (c + 1 < NCHUNK) STAGE(p ^ 1, c + 1);

        // prefetch next chunk's emb block (2 coalesced dwordx4; used next iter)
        float4 eN0 = eC0, eN1 = eC1;
        if (c + 1 < NCHUNK) {
            const float4* nb = ew + (size_t)(c + 1) * 128;
            eN0 = nb[2 * lane]; eN1 = nb[2 * lane + 1];
        }

        // lane l holds emb[8w+(l&7)][64c + 8*(l>>3) + j], j=0..7 in ej[]
        const float ej[8] = {eC0.x, eC0.y, eC0.z, eC0.w,
                             eC1.x, eC1.y, eC1.z, eC1.w};

#pragma unroll
        for (int oct = 0; oct < 8; ++oct) {        // 8 k-values per oct
            const float4 a0 = xs[p][lane     ][(2 * oct)     ^ sw];
            const float4 a1 = xs[p][lane     ][(2 * oct + 1) ^ sw];
            const float4 b0 = xs[p][lane + 64][(2 * oct)     ^ sw];
            const float4 b1 = xs[p][lane + 64][(2 * oct + 1) ^ sw];
            const float xA[8] = {a0.x, a0.y, a0.z, a0.w, a1.x, a1.y, a1.z, a1.w};
            const float xB[8] = {b0.x, b0.y, b0.z, b0.w, b1.x, b1.y, b1.z, b1.w};

#pragma unroll
            for (int e = 0; e < 8; ++e) {
                const int srcl = 8 * oct + e;      // lane holding (e, this oct)
#pragma unroll
                for (int j = 0; j < 8; ++j) {
                    const float s = __uint_as_float(
                        __builtin_amdgcn_readlane(__float_as_uint(ej[j]), srcl));
                    accA[e] = fmaf(s, xA[j], accA[e]);
                    accB[e] = fmaf(s, xB[j], accB[e]);
                }
            }
        }
        eC0 = eN0; eC1 = eN1;
        p ^= 1;
    }

    // ---- per-lane top-2 over 8 local experts, both tokens ----
    {
        float v1 = accA[0], v2 = -INFINITY; int j1 = 0, j2 = 0;
#pragma unroll
        for (int j = 1; j < 8; ++j) {
            if (accA[j] > v1)      { v2 = v1; j2 = j1; v1 = accA[j]; j1 = j; }
            else if (accA[j] > v2) { v2 = accA[j]; j2 = j; }
        }
        float4 cd; cd.x = v1; cd.y = __int_as_float(8 * w + j1);
        cd.z = v2; cd.w = __int_as_float(8 * w + j2);
        cand[w][0][lane] = cd;
    }
    {
        float v1 = accB[0], v2 = -INFINITY; int j1 = 0, j2 = 0;
#pragma unroll
        for (int j = 1; j < 8; ++j) {
            if (accB[j] > v1)      { v2 = v1; j2 = j1; v1 = accB[j]; j1 = j; }
            else if (accB[j] > v2) { v2 = accB[j]; j2 = j; }
        }
        float4 cd; cd.x = v1; cd.y = __int_as_float(8 * w + j1);
        cd.z = v2; cd.w = __int_as_float(8 * w + j2);
        cand[w][1][lane] = cd;
    }
    __syncthreads();

    // ---- merge 8 e-groups per token (ascending group => lowest-idx tie-break) ----
    if (tid < TPB) {
        const int half = tid >> 6, l = tid & 63;
        float V1 = -INFINITY, V2 = -INFINITY; int E1 = 0, E2 = 0;
#pragma unroll
        for (int ww = 0; ww < 8; ++ww) {
            const float4 q = cand[ww][half][l];
            const float a = q.x; const int ea = __float_as_int(q.y);
            const float b = q.z; const int eb = __float_as_int(q.w);
            if (a > V1)      { V2 = V1; E2 = E1; V1 = a; E1 = ea; }
            else if (a > V2) { V2 = a; E2 = ea; }
            if (b > V1)      { V2 = V1; E2 = E1; V1 = b; E1 = eb; }
            else if (b > V2) { V2 = b; E2 = eb; }
        }
        const float et = expf(V2 - V1);
        float4 c2;
        c2.x = 1.f / (1.f + et);
        c2.y = et / (1.f + et);
        c2.z = __int_as_float(E1);
        c2.w = __int_as_float(E2);
        cand2[tid] = c2;
    }
    __syncthreads();

    // ---- fully coalesced output: 2048 float4 per block (128 tok x 16 quads) ----
#pragma unroll
    for (int jj = 0; jj < 4; ++jj) {
        const int G = jj * NTHREADS + tid;         // 0..2047
        const int t = G >> 4, q = G & 15;
        const float4 c2 = cand2[t];
        const int E1 = __float_as_int(c2.z), E2 = __float_as_int(c2.w);
        float4 o;
        float* of = (float*)&o;
#pragma unroll
        for (int i = 0; i < 4; ++i) {
            const int e = 4 * q + i;
            of[i] = (e == E1) ? c2.x : (e == E2) ? c2.y : 0.f;
        }
        *(float4*)(out + (size_t)(tok0 + t) * NEXP + q * 4) = o;
    }
#undef STAGE
}

extern "C" void kernel_launch(void* const* d_in, const int* in_sizes, int n_in,
                              void* d_out, int out_size, void* d_ws, size_t ws_size,
                              hipStream_t stream)
{
    const float* x   = (const float*)d_in[0];
    const float* emb = (const float*)d_in[1];
    float* out = (float*)d_out;
    float4* ewp = (float4*)d_ws;                 // 256 KiB prepacked emb

    prepack_kernel<<<64, 256, 0, stream>>>(emb, ewp);

    const int n_tokens = in_sizes[0] / HDIM;     // 32768
    const int nblocks  = n_tokens / TPB;         // 256

    router_kernel<<<nblocks, NTHREADS, 0, stream>>>(x, ewp, out);
}

// Round 8
// 88.841 us; speedup vs baseline: 40.8479x; 1.0207x over previous
//
#include <hip/hip_runtime.h>
#include <math.h>

// Router: scores = x @ emb^T [32768 x 64] fp32, top-2 + 2-way softmax scatter.
//
// Readlane-broadcast GEMM (round-7 structure) reshaped for occupancy:
// ONE 1024-thread block per CU (16 waves), wave owns 4 experts, lane owns 2
// tokens (lane, lane+64). Per wave-chunk: 512 FMA + 256 readlane (same 2:1
// amortization as round 7) but 4 waves/SIMD now hide readlane->fmac SGPR
// hazards, ds_read latency, and barrier drains (round 7: 84KB LDS forced
// 1x512-thr block/CU = 2 waves/SIMD -> VALUBusy 55%).
// emb chunk: 1 float4/lane from prepacked layout, prefetched 1 chunk ahead
// (4 VGPRs -- no round-5-style spill). x staged via global_load_lds with
// XOR-quad-swizzle folded into the global source (0 conflicts measured).

constexpr int HDIM = 1024;
constexpr int NEXP = 64;
constexpr int TPB  = 128;           // tokens per block
constexpr int NQ   = 16;            // quads per 64-k chunk row
constexpr int NTHREADS = 1024;      // 16 waves
constexpr int NCHUNK = 16;

// prepack: ewp[(w*16 + c)*64 + l] = emb[4w + (l&3)][64c + 4*(l>>2) .. +3]
// per (wave,chunk): 64 consecutive float4 (1 KiB); lane l reads float4 #l.
__global__ __launch_bounds__(256)
void prepack_kernel(const float* __restrict__ emb, float4* __restrict__ ewp)
{
    const int f = blockIdx.x * 256 + threadIdx.x;   // 0..16383
    const int l = f & 63;
    const int c = (f >> 6) & 15;
    const int w = f >> 10;
    const int e = 4 * w + (l & 3);
    const int k = 64 * c + 4 * (l >> 2);
    ewp[f] = *(const float4*)(emb + (size_t)e * HDIM + k);
}

__global__ __launch_bounds__(NTHREADS, 1)
void router_kernel(const float* __restrict__ x,
                   const float4* __restrict__ ewp,
                   float* __restrict__ out)
{
    __shared__ float4 xs[2][TPB][NQ];     // 64 KiB, x[token][quad^(token&15)]
    __shared__ float4 cand[16][2][64];    // 32 KiB  (v1,e1,v2,e2) per wave/half
    __shared__ float4 cand2[TPB];         // 2 KiB   (p1,p2,E1,E2) per token

    const int tid  = threadIdx.x;
    const int lane = tid & 63;
    const int w    = tid >> 6;            // e-group: experts [4w, 4w+4)
    const int tok0 = blockIdx.x * TPB;
    const int sw   = lane & 15;

    // Stage chunk C of x (128 rows x 64 k = 32 KB) into buffer P.
    // Linear dest (gload_lds requirement); XOR swizzle on the global source.
#define STAGE(P, C)                                                            \
    do {                                                                       \
        _Pragma("unroll")                                                      \
        for (int jj = 0; jj < 2; ++jj) {                                       \
            const int g_ = jj * NTHREADS + tid;                                \
            const int r_ = g_ >> 4, q_ = g_ & 15;                              \
            const float* src = x + (size_t)(tok0 + r_) * HDIM + (C) * 64       \
                                 + ((q_ ^ (r_ & 15)) * 4);                     \
            __builtin_amdgcn_global_load_lds(                                  \
                (const __attribute__((address_space(1))) void*)src,            \
                (__attribute__((address_space(3))) void*)&xs[P][r_][q_],       \
                16, 0, 0);                                                     \
        }                                                                      \
    } while (0)

    float accA[4], accB[4];
#pragma unroll
    for (int i = 0; i < 4; ++i) { accA[i] = 0.f; accB[i] = 0.f; }

    const float4* ew = ewp + (size_t)w * 1024;     // this wave's packed slice
    float4 eC = ew[lane];                           // chunk 0: lane = (quad<<2)|e

    STAGE(0, 0);
    int p = 0;

#pragma unroll 1
    for (int c = 0; c < NCHUNK; ++c) {
        __syncthreads();                           // xs[p] staged
        if (c + 1 < NCHUNK) STAGE(p ^ 1, c + 1);

        // prefetch next chunk's emb float4 (coalesced; consumed next iter)
        float4 eN = eC;
        if (c + 1 < NCHUNK) eN = ew[(c + 1) * 64 + lane];

        // lane l holds emb[4w+(l&3)][64c + 4*(l>>2) + j], j=0..3
        const float ej[4] = {eC.x, eC.y, eC.z, eC.w};

#pragma unroll
        for (int oct = 0; oct < 8; ++oct) {        // k = 8*oct .. 8*oct+7
            const float4 a0 = xs[p][lane     ][(2 * oct)     ^ sw];
            const float4 a1 = xs[p][lane     ][(2 * oct + 1) ^ sw];
            const float4 b0 = xs[p][lane + 64][(2 * oct)     ^ sw];
            const float4 b1 = xs[p][lane + 64][(2 * oct + 1) ^ sw];
            const float xA[8] = {a0.x, a0.y, a0.z, a0.w, a1.x, a1.y, a1.z, a1.w};
            const float xB[8] = {b0.x, b0.y, b0.z, b0.w, b1.x, b1.y, b1.z, b1.w};

#pragma unroll
            for (int e = 0; e < 4; ++e) {
#pragma unroll
                for (int j = 0; j < 8; ++j) {
                    // lane holding k = 8*oct+j for expert e of this group
                    const int srcl = 4 * (2 * oct + (j >> 2)) + e;
                    const float s = __uint_as_float(
                        __builtin_amdgcn_readlane(__float_as_uint(ej[j & 3]),
                                                  srcl));
                    accA[e] = fmaf(s, xA[j], accA[e]);
                    accB[e] = fmaf(s, xB[j], accB[e]);
                }
            }
        }
        eC = eN;
        p ^= 1;
    }

    // ---- per-lane top-2 over 4 local experts, both tokens ----
    {
        float v1 = accA[0], v2 = -INFINITY; int j1 = 0, j2 = 0;
#pragma unroll
        for (int j = 1; j < 4; ++j) {
            if (accA[j] > v1)      { v2 = v1; j2 = j1; v1 = accA[j]; j1 = j; }
            else if (accA[j] > v2) { v2 = accA[j]; j2 = j; }
        }
        float4 cd; cd.x = v1; cd.y = __int_as_float(4 * w + j1);
        cd.z = v2; cd.w = __int_as_float(4 * w + j2);
        cand[w][0][lane] = cd;
    }
    {
        float v1 = accB[0], v2 = -INFINITY; int j1 = 0, j2 = 0;
#pragma unroll
        for (int j = 1; j < 4; ++j) {
            if (accB[j] > v1)      { v2 = v1; j2 = j1; v1 = accB[j]; j1 = j; }
            else if (accB[j] > v2) { v2 = accB[j]; j2 = j; }
        }
        float4 cd; cd.x = v1; cd.y = __int_as_float(4 * w + j1);
        cd.z = v2; cd.w = __int_as_float(4 * w + j2);
        cand[w][1][lane] = cd;
    }
    __syncthreads();

    // ---- merge 16 e-groups per token (ascending group => lowest-idx ties) ----
    if (tid < TPB) {
        const int half = tid >> 6, l = tid & 63;
        float V1 = -INFINITY, V2 = -INFINITY; int E1 = 0, E2 = 0;
#pragma unroll
        for (int ww = 0; ww < 16; ++ww) {
            const float4 q = cand[ww][half][l];
            const float a = q.x; const int ea = __float_as_int(q.y);
            const float b = q.z; const int eb = __float_as_int(q.w);
            if (a > V1)      { V2 = V1; E2 = E1; V1 = a; E1 = ea; }
            else if (a > V2) { V2 = a; E2 = ea; }
            if (b > V1)      { V2 = V1; E2 = E1; V1 = b; E1 = eb; }
            else if (b > V2) { V2 = b; E2 = eb; }
        }
        const float et = expf(V2 - V1);
        float4 c2;
        c2.x = 1.f / (1.f + et);
        c2.y = et / (1.f + et);
        c2.z = __int_as_float(E1);
        c2.w = __int_as_float(E2);
        cand2[tid] = c2;
    }
    __syncthreads();

    // ---- fully coalesced output: 2048 float4 per block (128 tok x 16 quads) ----
#pragma unroll
    for (int jj = 0; jj < 2; ++jj) {
        const int G = jj * NTHREADS + tid;         // 0..2047
        const int t = G >> 4, q = G & 15;
        const float4 c2 = cand2[t];
        const int E1 = __float_as_int(c2.z), E2 = __float_as_int(c2.w);
        float4 o;
        float* of = (float*)&o;
#pragma unroll
        for (int i = 0; i < 4; ++i) {
            const int e = 4 * q + i;
            of[i] = (e == E1) ? c2.x : (e == E2) ? c2.y : 0.f;
        }
        *(float4*)(out + (size_t)(tok0 + t) * NEXP + q * 4) = o;
    }
#undef STAGE
}

extern "C" void kernel_launch(void* const* d_in, const int* in_sizes, int n_in,
                              void* d_out, int out_size, void* d_ws, size_t ws_size,
                              hipStream_t stream)
{
    const float* x   = (const float*)d_in[0];
    const float* emb = (const float*)d_in[1];
    float* out = (float*)d_out;
    float4* ewp = (float4*)d_ws;                 // 256 KiB prepacked emb

    prepack_kernel<<<64, 256, 0, stream>>>(emb, ewp);

    const int n_tokens = in_sizes[0] / HDIM;     // 32768
    const int nblocks  = n_tokens / TPB;         // 256

    router_kernel<<<nblocks, NTHREADS, 0, stream>>>(x, ewp, out);
}

// Round 9
// 60.425 us; speedup vs baseline: 60.0577x; 1.4703x over previous
//
#include <hip/hip_runtime.h>
#include <math.h>
#include <stdint.h>

// Router: scores = x @ emb^T [32768 x 64] fp32-accurate, top-2 + 2-way softmax.
//
// Error-free split-bf16 MFMA: x and emb are RNE-split into 3 bf16 limbs each
// (exact subtractions; residual <= 2^-24). Six limb-product MFMA passes
// (00,01,10,11,02,20) accumulate in fp32 -> score error ~3e-7, BELOW the
// previous fp32-VALU kernel's ~8e-7 vs reference. Moves the GEMM off the
// 157-TF fp32 VALU (rounds 2-8 ceiling ~41-54 us) onto the 2.5-PF matrix
// pipe: 25.8 GF effective = 3.1 us MFMA; memory floor 21.6 us dominates.
//
// No LDS staging: x global->reg->split->MFMA (2-step lookahead keeps ~32KB/CU
// in flight = HBM-saturating); emb limbs prepacked in ws as ready B-frags
// (384 KB, L1/L2-resident, 1-tile register lookahead).
// Wave = 16 tokens x 64 experts (4 N-tiles of mfma_f32_16x16x32_bf16).
// C-layout (m89): col=lane&15, row=(lane>>4)*4+reg -> top-2 via 4-step
// shfl_xor merge over the 16-lane group, lowest-index tie-break.

typedef __attribute__((ext_vector_type(8))) short short8;
typedef __attribute__((ext_vector_type(4))) float f32x4;

constexpr int HDIM = 1024;
constexpr int NEXP = 64;
constexpr int TPB  = 64;            // tokens per block (4 waves x 16)
constexpr int NTHREADS = 256;
constexpr int NKK  = 32;            // K-steps of 32

__device__ __forceinline__ uint32_t cvtpk_bf16(float lo, float hi) {
    uint32_t r;
    asm("v_cvt_pk_bf16_f32 %0, %1, %2" : "=v"(r) : "v"(lo), "v"(hi));
    return r;
}

// RNE 3-limb bf16 split of 8 fp32 values; outputs packed frag words.
__device__ __forceinline__ void split8(const float4& A, const float4& B,
                                       uint32_t w0[4], uint32_t w1[4],
                                       uint32_t w2[4])
{
    const float p[8] = {A.x, A.y, A.z, A.w, B.x, B.y, B.z, B.w};
#pragma unroll
    for (int m = 0; m < 4; ++m) {
        const float lo = p[2 * m], hi = p[2 * m + 1];
        const uint32_t c0 = cvtpk_bf16(lo, hi);
        const float l0 = __uint_as_float(c0 << 16);
        const float h0 = __uint_as_float(c0 & 0xFFFF0000u);
        const float rl = lo - l0, rh = hi - h0;         // exact
        const uint32_t c1 = cvtpk_bf16(rl, rh);
        const float l1 = __uint_as_float(c1 << 16);
        const float h1 = __uint_as_float(c1 & 0xFFFF0000u);
        const uint32_t c2 = cvtpk_bf16(rl - l1, rh - h1);
        w0[m] = c0; w1[m] = c1; w2[m] = c2;
    }
}

__device__ __forceinline__ short8 frag_of(uint32_t a, uint32_t b,
                                          uint32_t c, uint32_t d) {
    union { uint4 u; short8 s; } cv;
    cv.u = make_uint4(a, b, c, d);
    return cv.s;
}
__device__ __forceinline__ short8 frag_of4(const uint4& v) {
    union { uint4 u; short8 s; } cv;
    cv.u = v;
    return cv.s;
}

// prepack: B-frags for mfma. wsb[f] with f=[kk][t][lane]: lane l holds
// emb[t*16+(l&15)][kk*32+(l>>4)*8 .. +7] as bf16x8; three limb arrays.
__global__ __launch_bounds__(256)
void prepack_kernel(const float* __restrict__ emb, uint4* __restrict__ wsb)
{
    const int f  = blockIdx.x * 256 + threadIdx.x;   // 0..8191
    const int l  = f & 63, t = (f >> 6) & 3, kk = f >> 8;
    const int e  = t * 16 + (l & 15);
    const int k0 = kk * 32 + (l >> 4) * 8;
    const float4 A = *(const float4*)(emb + (size_t)e * HDIM + k0);
    const float4 B = *(const float4*)(emb + (size_t)e * HDIM + k0 + 4);
    uint32_t w0[4], w1[4], w2[4];
    split8(A, B, w0, w1, w2);
    wsb[f]         = make_uint4(w0[0], w0[1], w0[2], w0[3]);
    wsb[f + 8192]  = make_uint4(w1[0], w1[1], w1[2], w1[3]);
    wsb[f + 16384] = make_uint4(w2[0], w2[1], w2[2], w2[3]);
}

__global__ __launch_bounds__(NTHREADS, 2)
void router_kernel(const float* __restrict__ x,
                   const uint4* __restrict__ wsb,
                   float* __restrict__ out)
{
    __shared__ float4 cand2[TPB];    // (p1,p2,E1,E2) per token

    const int tid  = threadIdx.x;
    const int lane = tid & 63;
    const int w    = tid >> 6;
    const int tok0 = blockIdx.x * TPB;
    const int col  = lane & 15;      // token row (A) / expert col (C)
    const int grp  = lane >> 4;

    // A-operand source: lane holds token (w*16+col), k-slice grp*8..+7 per kk
    const float* xrow = x + (size_t)(tok0 + w * 16 + col) * HDIM + grp * 8;

    f32x4 acc0 = {0,0,0,0}, acc1 = {0,0,0,0}, acc2 = {0,0,0,0}, acc3 = {0,0,0,0};

    // x 2-step lookahead
    float4 xc0 = *(const float4*)(xrow);
    float4 xc1 = *(const float4*)(xrow + 4);
    float4 xn0 = *(const float4*)(xrow + 32);
    float4 xn1 = *(const float4*)(xrow + 36);

    // B 1-tile lookahead (L1/L2-resident)
    uint4 b0c = wsb[lane], b1c = wsb[8192 + lane], b2c = wsb[16384 + lane];
    uint4 b0n = b0c, b1n = b1c, b2n = b2c;

#pragma unroll 1
    for (int kk = 0; kk < NKK; ++kk) {
        uint32_t w0[4], w1[4], w2[4];
        split8(xc0, xc1, w0, w1, w2);
        const short8 fa0 = frag_of(w0[0], w0[1], w0[2], w0[3]);
        const short8 fa1 = frag_of(w1[0], w1[1], w1[2], w1[3]);
        const short8 fa2 = frag_of(w2[0], w2[1], w2[2], w2[3]);

        xc0 = xn0; xc1 = xn1;
        if (kk + 2 < NKK) {
            xn0 = *(const float4*)(xrow + (kk + 2) * 32);
            xn1 = *(const float4*)(xrow + (kk + 2) * 32 + 4);
        }

#pragma unroll
        for (int t = 0; t < 4; ++t) {
            if (!(kk == NKK - 1 && t == 3)) {
                const int nidx = (t == 3) ? ((kk + 1) * 4) * 64 + lane
                                          : (kk * 4 + t + 1) * 64 + lane;
                b0n = wsb[nidx];
                b1n = wsb[8192 + nidx];
                b2n = wsb[16384 + nidx];
            }
            const short8 fb0 = frag_of4(b0c);
            const short8 fb1 = frag_of4(b1c);
            const short8 fb2 = frag_of4(b2c);
            f32x4 a = (t == 0) ? acc0 : (t == 1) ? acc1 : (t == 2) ? acc2 : acc3;
            a = __builtin_amdgcn_mfma_f32_16x16x32_bf16(fa2, fb0, a, 0, 0, 0);
            a = __builtin_amdgcn_mfma_f32_16x16x32_bf16(fa0, fb2, a, 0, 0, 0);
            a = __builtin_amdgcn_mfma_f32_16x16x32_bf16(fa1, fb1, a, 0, 0, 0);
            a = __builtin_amdgcn_mfma_f32_16x16x32_bf16(fa1, fb0, a, 0, 0, 0);
            a = __builtin_amdgcn_mfma_f32_16x16x32_bf16(fa0, fb1, a, 0, 0, 0);
            a = __builtin_amdgcn_mfma_f32_16x16x32_bf16(fa0, fb0, a, 0, 0, 0);
            if      (t == 0) acc0 = a;
            else if (t == 1) acc1 = a;
            else if (t == 2) acc2 = a;
            else             acc3 = a;
            b0c = b0n; b1c = b1n; b2c = b2n;
        }
    }

    // ---- top-2 epilogue. Lane holds tokens r=grp*4+i (i=reg) for experts
    // t*16+col. Merge across the 16-lane group (masks 1,2,4,8), lowest
    // expert index wins exact ties.
#define INS(v, e)                                                              \
    do {                                                                       \
        const float _v = (v); const int _e = (e);                              \
        if (_v > V1 || (_v == V1 && _e < E1)) {                                \
            V2 = V1; E2 = E1; V1 = _v; E1 = _e;                                \
        } else if (_v > V2 || (_v == V2 && _e < E2)) {                         \
            V2 = _v; E2 = _e;                                                  \
        }                                                                      \
    } while (0)

#pragma unroll
    for (int i = 0; i < 4; ++i) {
        float V1 = acc0[i]; int E1 = col;
        float V2 = -INFINITY; int E2 = NEXP;
        INS(acc1[i], 16 + col);
        INS(acc2[i], 32 + col);
        INS(acc3[i], 48 + col);
#pragma unroll
        for (int m = 1; m <= 8; m <<= 1) {
            const float pv1 = __shfl_xor(V1, m, 64);
            const int   pe1 = __shfl_xor(E1, m, 64);
            const float pv2 = __shfl_xor(V2, m, 64);
            const int   pe2 = __shfl_xor(E2, m, 64);
            INS(pv1, pe1);
            INS(pv2, pe2);
        }
        if (col == 0) {
            const float et = expf(V2 - V1);
            float4 c;
            c.x = 1.f / (1.f + et);
            c.y = et / (1.f + et);
            c.z = __int_as_float(E1);
            c.w = __int_as_float(E2);
            cand2[w * 16 + grp * 4 + i] = c;
        }
    }
#undef INS
    __syncthreads();

    // ---- coalesced output: 64 tokens x 16 quads = 1024 float4 ----
#pragma unroll
    for (int jj = 0; jj < 4; ++jj) {
        const int G = jj * NTHREADS + tid;     // 0..1023
        const int tt = G >> 4, q = G & 15;
        const float4 c = cand2[tt];
        const int E1 = __float_as_int(c.z), E2 = __float_as_int(c.w);
        float4 o;
        float* of = (float*)&o;
#pragma unroll
        for (int ii = 0; ii < 4; ++ii) {
            const int e = 4 * q + ii;
            of[ii] = (e == E1) ? c.x : (e == E2) ? c.y : 0.f;
        }
        *(float4*)(out + (size_t)(tok0 + tt) * NEXP + q * 4) = o;
    }
}

extern "C" void kernel_launch(void* const* d_in, const int* in_sizes, int n_in,
                              void* d_out, int out_size, void* d_ws, size_t ws_size,
                              hipStream_t stream)
{
    const float* x   = (const float*)d_in[0];
    const float* emb = (const float*)d_in[1];
    float* out = (float*)d_out;
    uint4* wsb = (uint4*)d_ws;                   // 384 KiB: 3 limb B-frag arrays

    prepack_kernel<<<32, 256, 0, stream>>>(emb, wsb);

    const int n_tokens = in_sizes[0] / HDIM;     // 32768
    const int nblocks  = n_tokens / TPB;         // 512

    router_kernel<<<nblocks, NTHREADS, 0, stream>>>(x, wsb, out);
}